// Round 1
// baseline (770.856 us; speedup 1.0000x reference)
//
#include <hip/hip_runtime.h>

#define NNODES 50000
#define NFEAT  128
#define NEDGES 600000
#define HID    256
#define HID2   128
#define LEAKY  0.01f

// ---------------------------------------------------------------------------
// Kernel 1: PQ[n][0:256]   = x[n] @ W1[0:128, :]     (P: row-part)
//           PQ[n][256:512] = x[n] @ W1[128:256, :]   (Q: col-part)
// 16 nodes per block, 256 threads; thread t computes col t of P and col t of Q
// for all 16 nodes. W1 stays in L2 (256 KB, read once per block).
// ---------------------------------------------------------------------------
__global__ __launch_bounds__(256) void precompute_pq(
    const float* __restrict__ x, const float* __restrict__ W1,
    float* __restrict__ PQ) {
  const int t  = threadIdx.x;
  const int n0 = blockIdx.x * 16;

  __shared__ float xT[128][17];  // +1 pad: conflict-free staging writes
  for (int idx = t; idx < 16 * 128; idx += 256) {
    const int node = idx >> 7, f = idx & 127;
    const int n = n0 + node;
    xT[f][node] = (n < NNODES) ? x[(size_t)n * NFEAT + f] : 0.f;
  }
  __syncthreads();

  float accP[16], accQ[16];
#pragma unroll
  for (int j = 0; j < 16; ++j) { accP[j] = 0.f; accQ[j] = 0.f; }

  for (int f = 0; f < 128; ++f) {
    const float w0 = W1[f * HID + t];            // top half rows
    const float w1 = W1[(128 + f) * HID + t];    // bottom half rows
#pragma unroll
    for (int j = 0; j < 16; ++j) {
      const float a = xT[f][j];                  // LDS broadcast
      accP[j] = fmaf(a, w0, accP[j]);
      accQ[j] = fmaf(a, w1, accQ[j]);
    }
  }

#pragma unroll
  for (int j = 0; j < 16; ++j) {
    const int n = n0 + j;
    if (n < NNODES) {
      PQ[(size_t)n * 512 + t]       = accP[j];
      PQ[(size_t)n * 512 + 256 + t] = accQ[j];
    }
  }
}

// ---------------------------------------------------------------------------
// Kernel 2: per 32-edge tile:
//   h1[e][:] = relu(P[row_e] + Q[col_e] + b1)          (gather, LDS 32 KB)
//   C = h1 @ W2  (fp32 register-blocked 4x4, W2 from L2 via float4)
//   out[e] = leaky_relu(C + b2) @ W3 + b3              (fused epilogue)
// 256 threads = 8 tr-groups (4 edges each) x 32 tc-groups (4 cols each).
// ---------------------------------------------------------------------------
template <bool PRECOMP>
__global__ __launch_bounds__(256) void edge_mlp(
    const float* __restrict__ x, const int* __restrict__ ei,
    const float* __restrict__ W1, const float* __restrict__ b1,
    const float* __restrict__ W2, const float* __restrict__ b2,
    const float* __restrict__ W3, const float* __restrict__ b3,
    const float* __restrict__ PQ, float* __restrict__ out) {
  const int t  = threadIdx.x;
  const int e0 = blockIdx.x * 32;

  __shared__ __align__(16) float h1s[32 * HID];  // 32 KB
  __shared__ int eidx[2][32];

  if (t < 32)       eidx[0][t]      = ei[e0 + t];            // rows
  else if (t < 64)  eidx[1][t - 32] = ei[NEDGES + e0 + (t - 32)];  // cols
  __syncthreads();

  const float b1r = b1[t];

  if constexpr (PRECOMP) {
    // h1[e][t] = relu(P[row_e][t] + Q[col_e][t] + b1[t])
#pragma unroll 4
    for (int e = 0; e < 32; ++e) {
      const int r = eidx[0][e], c = eidx[1][e];
      const float v = PQ[(size_t)r * 512 + t] + PQ[(size_t)c * 512 + 256 + t] + b1r;
      h1s[e * HID + t] = fmaxf(v, 0.f);
    }
  } else {
    // Fallback (ws too small): compute layer 1 directly from x and W1.
    __shared__ float xr[32][128];
    __shared__ float xc[32][128];
    for (int idx = t; idx < 32 * 128; idx += 256) {
      const int e = idx >> 7, f = idx & 127;
      xr[e][f] = x[(size_t)eidx[0][e] * NFEAT + f];
      xc[e][f] = x[(size_t)eidx[1][e] * NFEAT + f];
    }
    __syncthreads();
    float s[32];
#pragma unroll
    for (int e = 0; e < 32; ++e) s[e] = b1r;
    for (int f = 0; f < 128; ++f) {
      const float wr = W1[f * HID + t];
      const float wb = W1[(128 + f) * HID + t];
#pragma unroll
      for (int e = 0; e < 32; ++e)
        s[e] = fmaf(xr[e][f], wr, fmaf(xc[e][f], wb, s[e]));
    }
#pragma unroll
    for (int e = 0; e < 32; ++e) h1s[e * HID + t] = fmaxf(s[e], 0.f);
  }
  __syncthreads();

  // ----- GEMM: 32x128 = h1(32x256) @ W2(256x128), 4x4 per thread -----
  const int tr = t >> 5;   // 0..7  -> edges 4*tr..4*tr+3
  const int tc = t & 31;   // 0..31 -> cols  4*tc..4*tc+3

  float acc[4][4];
#pragma unroll
  for (int i = 0; i < 4; ++i)
#pragma unroll
    for (int j = 0; j < 4; ++j) acc[i][j] = 0.f;

  const float4* __restrict__ W2v = reinterpret_cast<const float4*>(W2);
  const float4* __restrict__ h1v = reinterpret_cast<const float4*>(h1s);

  for (int k = 0; k < HID; k += 4) {
    float4 a[4];
#pragma unroll
    for (int i = 0; i < 4; ++i)
      a[i] = h1v[((4 * tr + i) * HID + k) >> 2];   // LDS, 2-addr broadcast
    float4 b[4];
#pragma unroll
    for (int kk = 0; kk < 4; ++kk)
      b[kk] = W2v[(k + kk) * 32 + tc];             // L2-hot, coalesced
#pragma unroll
    for (int i = 0; i < 4; ++i) {
      const float* av = reinterpret_cast<const float*>(&a[i]);
#pragma unroll
      for (int kk = 0; kk < 4; ++kk) {
        const float* bv = reinterpret_cast<const float*>(&b[kk]);
#pragma unroll
        for (int j = 0; j < 4; ++j)
          acc[i][j] = fmaf(av[kk], bv[j], acc[i][j]);
      }
    }
  }

  // ----- epilogue: leaky_relu(C + b2) @ W3 + b3, reduce over tc -----
  float w3r[4], b2r[4];
#pragma unroll
  for (int j = 0; j < 4; ++j) {
    w3r[j] = W3[4 * tc + j];
    b2r[j] = b2[4 * tc + j];
  }
  const float b3v = b3[0];

  float partial[4];
#pragma unroll
  for (int i = 0; i < 4; ++i) {
    float s = 0.f;
#pragma unroll
    for (int j = 0; j < 4; ++j) {
      float h = acc[i][j] + b2r[j];
      h = (h > 0.f) ? h : LEAKY * h;
      s = fmaf(h, w3r[j], s);
    }
    partial[i] = s;
  }

  // reduce across the 32 tc-lanes (tr is uniform within each 32-lane group)
#pragma unroll
  for (int m = 16; m >= 1; m >>= 1) {
#pragma unroll
    for (int i = 0; i < 4; ++i)
      partial[i] += __shfl_xor(partial[i], m, 32);
  }

  if (tc == 0) {
#pragma unroll
    for (int i = 0; i < 4; ++i)
      out[e0 + 4 * tr + i] = partial[i] + b3v;
  }
}

extern "C" void kernel_launch(void* const* d_in, const int* in_sizes, int n_in,
                              void* d_out, int out_size, void* d_ws, size_t ws_size,
                              hipStream_t stream) {
  const float* x  = (const float*)d_in[0];
  const int*   ei = (const int*)d_in[1];
  const float* W1 = (const float*)d_in[2];
  const float* b1 = (const float*)d_in[3];
  const float* W2 = (const float*)d_in[4];
  const float* b2 = (const float*)d_in[5];
  const float* W3 = (const float*)d_in[6];
  const float* b3 = (const float*)d_in[7];
  float* out = (float*)d_out;

  const size_t pq_bytes = (size_t)NNODES * 512 * sizeof(float);
  const int n_tiles = NEDGES / 32;  // 18750, exact

  if (ws_size >= pq_bytes) {
    float* PQ = (float*)d_ws;
    precompute_pq<<<(NNODES + 15) / 16, 256, 0, stream>>>(x, W1, PQ);
    edge_mlp<true><<<n_tiles, 256, 0, stream>>>(x, ei, W1, b1, W2, b2, W3, b3, PQ, out);
  } else {
    edge_mlp<false><<<n_tiles, 256, 0, stream>>>(x, ei, W1, b1, W2, b2, W3, b3, nullptr, out);
  }
}

// Round 2
// 315.844 us; speedup vs baseline: 2.4406x; 2.4406x over previous
//
#include <hip/hip_runtime.h>

#define NNODES 50000
#define NFEAT  128
#define NEDGES 600000
#define HID    256
#define HID2   128
#define LEAKY  0.01f

typedef __attribute__((ext_vector_type(8))) short short8;
typedef __attribute__((ext_vector_type(4))) float floatx4;

// Split fp32 into bf16 hi + lo (truncation; residual ~2^-16 relative).
__device__ __forceinline__ void split_bf16(float x, unsigned short& hi, unsigned short& lo) {
  union { float f; unsigned u; } a;
  a.f = x;
  hi = (unsigned short)(a.u >> 16);
  union { float f; unsigned u; } h;
  h.u = (unsigned)hi << 16;
  union { float f; unsigned u; } r;
  r.f = x - h.f;
  lo = (unsigned short)(r.u >> 16);
}

// ---------------------------------------------------------------------------
// Kernel 0: pack W2 (256x128 fp32) into MFMA B-fragment order, bf16 hi/lo.
// For v_mfma_f32_16x16x32_bf16 B-operand: lane l holds B[(l>>4)*8+i][l&15].
// Layout: W2F[((ks*8+nf)*64 + lane)*8 + i], plane stride 32768 elems.
//   k = ks*32 + (l>>4)*8 + i, col = nf*16 + (l&15).
// ---------------------------------------------------------------------------
__global__ __launch_bounds__(256) void pack_w2(const float* __restrict__ W2,
                                               unsigned short* __restrict__ W2F) {
  const int idx = blockIdx.x * 256 + threadIdx.x;  // 0..32767
  if (idx >= 8 * 8 * 64 * 8) return;
  const int i  = idx & 7;
  const int l  = (idx >> 3) & 63;
  const int nf = (idx >> 9) & 7;
  const int ks = idx >> 12;
  const int k   = ks * 32 + (l >> 4) * 8 + i;
  const int col = nf * 16 + (l & 15);
  unsigned short hi, lo;
  split_bf16(W2[k * HID2 + col], hi, lo);
  W2F[idx]         = hi;
  W2F[32768 + idx] = lo;
}

// ---------------------------------------------------------------------------
// Kernel 1: PQ[n][0:256] = x[n] @ W1[0:128,:]; PQ[n][256:512] = x[n] @ W1[128:256,:]
// ---------------------------------------------------------------------------
__global__ __launch_bounds__(256) void precompute_pq(
    const float* __restrict__ x, const float* __restrict__ W1,
    float* __restrict__ PQ) {
  const int t  = threadIdx.x;
  const int n0 = blockIdx.x * 16;

  __shared__ float xT[128][17];
  for (int idx = t; idx < 16 * 128; idx += 256) {
    const int node = idx >> 7, f = idx & 127;
    const int n = n0 + node;
    xT[f][node] = (n < NNODES) ? x[(size_t)n * NFEAT + f] : 0.f;
  }
  __syncthreads();

  float accP[16], accQ[16];
#pragma unroll
  for (int j = 0; j < 16; ++j) { accP[j] = 0.f; accQ[j] = 0.f; }

  for (int f = 0; f < 128; ++f) {
    const float w0 = W1[f * HID + t];
    const float w1 = W1[(128 + f) * HID + t];
#pragma unroll
    for (int j = 0; j < 16; ++j) {
      const float a = xT[f][j];
      accP[j] = fmaf(a, w0, accP[j]);
      accQ[j] = fmaf(a, w1, accQ[j]);
    }
  }

#pragma unroll
  for (int j = 0; j < 16; ++j) {
    const int n = n0 + j;
    if (n < NNODES) {
      PQ[(size_t)n * 512 + t]       = accP[j];
      PQ[(size_t)n * 512 + 256 + t] = accQ[j];
    }
  }
}

// ---------------------------------------------------------------------------
// Kernel 2 (MFMA): per 32-edge tile.
//   gather: h1[e][c] = relu(P[row_e][c] + Q[col_e][c] + b1[c]) -> bf16 hi/lo
//           into XOR-swizzled LDS planes (row stride 512B -> swizzle needed).
//   GEMM:   C(32x128) = h1(32x256) @ W2, split-bf16 MFMA (hh + hl + lh).
//   epi:    out[e] = leakyrelu(C + b2) @ W3 + b3 (shuffle + LDS reduce).
// 4 waves; wave w owns cols [32w, 32w+32) (2 n-frags), all 32 rows (2 m-frags).
// ---------------------------------------------------------------------------
__global__ __launch_bounds__(256) void edge_mlp_mfma(
    const int* __restrict__ ei, const float* __restrict__ b1,
    const unsigned short* __restrict__ W2F, const float* __restrict__ b2,
    const float* __restrict__ W3, const float* __restrict__ b3,
    const float* __restrict__ PQ, float* __restrict__ out) {
  const int t  = threadIdx.x;
  const int e0 = blockIdx.x * 32;

  __shared__ __align__(16) unsigned short h1hi[32 * 256];  // 16 KB, swizzled
  __shared__ __align__(16) unsigned short h1lo[32 * 256];  // 16 KB, swizzled
  __shared__ int   eidx[2][32];
  __shared__ float outs[4][32];

  if (t < 32)      eidx[0][t]      = ei[e0 + t];
  else if (t < 64) eidx[1][t - 32] = ei[NEDGES + e0 + (t - 32)];
  __syncthreads();

  // ---- gather: thread handles col pair (2*c2, 2*c2+1) for 16 edges ----
  {
    const int c2 = t & 127;
    const int eg = t >> 7;  // 0/1 -> edges [16eg, 16eg+16)
    const float2 b1v = *reinterpret_cast<const float2*>(&b1[2 * c2]);
#pragma unroll 4
    for (int j = 0; j < 16; ++j) {
      const int e = eg * 16 + j;
      const int r = eidx[0][e], c = eidx[1][e];
      const float2 p = *reinterpret_cast<const float2*>(&PQ[(size_t)r * 512 + 2 * c2]);
      const float2 q = *reinterpret_cast<const float2*>(&PQ[(size_t)c * 512 + 256 + 2 * c2]);
      const float v0 = fmaxf(p.x + q.x + b1v.x, 0.f);
      const float v1 = fmaxf(p.y + q.y + b1v.y, 0.f);
      unsigned short h0, l0, h1_, l1;
      split_bf16(v0, h0, l0);
      split_bf16(v1, h1_, l1);
      const unsigned bt = (unsigned)(4 * c2) ^ ((unsigned)(e & 7) << 4);
      *reinterpret_cast<unsigned*>(reinterpret_cast<char*>(h1hi) + e * 512 + bt) =
          (unsigned)h0 | ((unsigned)h1_ << 16);
      *reinterpret_cast<unsigned*>(reinterpret_cast<char*>(h1lo) + e * 512 + bt) =
          (unsigned)l0 | ((unsigned)l1 << 16);
    }
  }
  __syncthreads();

  // ---- MFMA GEMM ----
  const int wid  = t >> 6;
  const int lane = t & 63;
  const int lr   = lane & 15;  // row (A) / col (B,D) within fragment
  const int kc   = lane >> 4;  // k-chunk

  floatx4 acc[2][2];
#pragma unroll
  for (int mf = 0; mf < 2; ++mf)
#pragma unroll
    for (int nf = 0; nf < 2; ++nf) acc[mf][nf] = (floatx4)0.f;

#pragma unroll
  for (int ks = 0; ks < 8; ++ks) {
    short8 ah[2], al[2];
#pragma unroll
    for (int mf = 0; mf < 2; ++mf) {
      const int row = mf * 16 + lr;
      const unsigned bt = (unsigned)(ks * 64 + kc * 16) ^ ((unsigned)(row & 7) << 4);
      ah[mf] = *reinterpret_cast<const short8*>(
          reinterpret_cast<const char*>(h1hi) + row * 512 + bt);
      al[mf] = *reinterpret_cast<const short8*>(
          reinterpret_cast<const char*>(h1lo) + row * 512 + bt);
    }
    short8 bh[2], bl[2];
#pragma unroll
    for (int nf = 0; nf < 2; ++nf) {
      const int nfg = wid * 2 + nf;
      const size_t off = ((size_t)(ks * 8 + nfg) * 64 + lane) * 8;
      bh[nf] = *reinterpret_cast<const short8*>(W2F + off);
      bl[nf] = *reinterpret_cast<const short8*>(W2F + 32768 + off);
    }
#pragma unroll
    for (int mf = 0; mf < 2; ++mf)
#pragma unroll
      for (int nf = 0; nf < 2; ++nf) {
        acc[mf][nf] = __builtin_amdgcn_mfma_f32_16x16x32_bf16(ah[mf], bh[nf], acc[mf][nf], 0, 0, 0);
        acc[mf][nf] = __builtin_amdgcn_mfma_f32_16x16x32_bf16(ah[mf], bl[nf], acc[mf][nf], 0, 0, 0);
        acc[mf][nf] = __builtin_amdgcn_mfma_f32_16x16x32_bf16(al[mf], bh[nf], acc[mf][nf], 0, 0, 0);
      }
  }

  // ---- epilogue: leaky_relu(C+b2) @ W3, reduce ----
  // D layout: col = lane&15 (+16*nf +32*wid), row = (lane>>4)*4 + reg (+16*mf)
  float w3v[2], b2v[2];
#pragma unroll
  for (int nf = 0; nf < 2; ++nf) {
    const int col = wid * 32 + nf * 16 + lr;
    w3v[nf] = W3[col];
    b2v[nf] = b2[col];
  }

  float part[2][4];
#pragma unroll
  for (int mf = 0; mf < 2; ++mf)
#pragma unroll
    for (int r = 0; r < 4; ++r) {
      float s = 0.f;
#pragma unroll
      for (int nf = 0; nf < 2; ++nf) {
        float h = acc[mf][nf][r] + b2v[nf];
        h = (h > 0.f) ? h : LEAKY * h;
        s = fmaf(h, w3v[nf], s);
      }
      part[mf][r] = s;
    }

  // sum across the 16 cols held by lanes lr=0..15 (same kc group)
#pragma unroll
  for (int m = 1; m <= 8; m <<= 1)
#pragma unroll
    for (int mf = 0; mf < 2; ++mf)
#pragma unroll
      for (int r = 0; r < 4; ++r) part[mf][r] += __shfl_xor(part[mf][r], m, 64);

  if (lr == 0) {
#pragma unroll
    for (int mf = 0; mf < 2; ++mf)
#pragma unroll
      for (int r = 0; r < 4; ++r) outs[wid][mf * 16 + kc * 4 + r] = part[mf][r];
  }
  __syncthreads();

  if (t < 32) {
    out[e0 + t] = outs[0][t] + outs[1][t] + outs[2][t] + outs[3][t] + b3[0];
  }
}

// ---------------------------------------------------------------------------
// Fallback (ws too small): direct fp32 path, no workspace.
// ---------------------------------------------------------------------------
__global__ __launch_bounds__(256) void edge_mlp_direct(
    const float* __restrict__ x, const int* __restrict__ ei,
    const float* __restrict__ W1, const float* __restrict__ b1,
    const float* __restrict__ W2, const float* __restrict__ b2,
    const float* __restrict__ W3, const float* __restrict__ b3,
    float* __restrict__ out) {
  const int t  = threadIdx.x;
  const int e0 = blockIdx.x * 32;

  __shared__ __align__(16) float h1s[32 * HID];
  __shared__ int eidx[2][32];

  if (t < 32)      eidx[0][t]      = ei[e0 + t];
  else if (t < 64) eidx[1][t - 32] = ei[NEDGES + e0 + (t - 32)];
  __syncthreads();

  const float b1r = b1[t];
  __shared__ float xr[32][128];
  __shared__ float xc[32][128];
  for (int idx = t; idx < 32 * 128; idx += 256) {
    const int e = idx >> 7, f = idx & 127;
    xr[e][f] = x[(size_t)eidx[0][e] * NFEAT + f];
    xc[e][f] = x[(size_t)eidx[1][e] * NFEAT + f];
  }
  __syncthreads();
  float s[32];
#pragma unroll
  for (int e = 0; e < 32; ++e) s[e] = b1r;
  for (int f = 0; f < 128; ++f) {
    const float wr = W1[f * HID + t];
    const float wb = W1[(128 + f) * HID + t];
#pragma unroll
    for (int e = 0; e < 32; ++e)
      s[e] = fmaf(xr[e][f], wr, fmaf(xc[e][f], wb, s[e]));
  }
#pragma unroll
  for (int e = 0; e < 32; ++e) h1s[e * HID + t] = fmaxf(s[e], 0.f);
  __syncthreads();

  const int tr = t >> 5;
  const int tc = t & 31;
  float acc[4][4];
#pragma unroll
  for (int i = 0; i < 4; ++i)
#pragma unroll
    for (int j = 0; j < 4; ++j) acc[i][j] = 0.f;

  const float4* __restrict__ W2v = reinterpret_cast<const float4*>(W2);
  const float4* __restrict__ h1v = reinterpret_cast<const float4*>(h1s);
  for (int k = 0; k < HID; k += 4) {
    float4 a[4];
#pragma unroll
    for (int i = 0; i < 4; ++i) a[i] = h1v[((4 * tr + i) * HID + k) >> 2];
    float4 b[4];
#pragma unroll
    for (int kk = 0; kk < 4; ++kk) b[kk] = W2v[(k + kk) * 32 + tc];
#pragma unroll
    for (int i = 0; i < 4; ++i) {
      const float* av = reinterpret_cast<const float*>(&a[i]);
#pragma unroll
      for (int kk = 0; kk < 4; ++kk) {
        const float* bv = reinterpret_cast<const float*>(&b[kk]);
#pragma unroll
        for (int j = 0; j < 4; ++j) acc[i][j] = fmaf(av[kk], bv[j], acc[i][j]);
      }
    }
  }

  float w3r[4], b2r[4];
#pragma unroll
  for (int j = 0; j < 4; ++j) {
    w3r[j] = W3[4 * tc + j];
    b2r[j] = b2[4 * tc + j];
  }
  const float b3v = b3[0];
  float partial[4];
#pragma unroll
  for (int i = 0; i < 4; ++i) {
    float sp = 0.f;
#pragma unroll
    for (int j = 0; j < 4; ++j) {
      float h = acc[i][j] + b2r[j];
      h = (h > 0.f) ? h : LEAKY * h;
      sp = fmaf(h, w3r[j], sp);
    }
    partial[i] = sp;
  }
#pragma unroll
  for (int m = 16; m >= 1; m >>= 1)
#pragma unroll
    for (int i = 0; i < 4; ++i) partial[i] += __shfl_xor(partial[i], m, 32);
  if (tc == 0) {
#pragma unroll
    for (int i = 0; i < 4; ++i) out[e0 + 4 * tr + i] = partial[i] + b3v;
  }
}

extern "C" void kernel_launch(void* const* d_in, const int* in_sizes, int n_in,
                              void* d_out, int out_size, void* d_ws, size_t ws_size,
                              hipStream_t stream) {
  const float* x  = (const float*)d_in[0];
  const int*   ei = (const int*)d_in[1];
  const float* W1 = (const float*)d_in[2];
  const float* b1 = (const float*)d_in[3];
  const float* W2 = (const float*)d_in[4];
  const float* b2 = (const float*)d_in[5];
  const float* W3 = (const float*)d_in[6];
  const float* b3 = (const float*)d_in[7];
  float* out = (float*)d_out;

  const size_t pq_bytes  = (size_t)NNODES * 512 * sizeof(float);  // 102,400,000
  const size_t w2f_bytes = (size_t)2 * 32768 * sizeof(unsigned short);
  const int n_tiles = NEDGES / 32;  // 18750

  if (ws_size >= pq_bytes + w2f_bytes) {
    float* PQ = (float*)d_ws;
    unsigned short* W2F = (unsigned short*)((char*)d_ws + pq_bytes);
    pack_w2<<<128, 256, 0, stream>>>(W2, W2F);
    precompute_pq<<<(NNODES + 15) / 16, 256, 0, stream>>>(x, W1, PQ);
    edge_mlp_mfma<<<n_tiles, 256, 0, stream>>>(ei, b1, W2F, b2, W3, b3, PQ, out);
  } else {
    edge_mlp_direct<<<n_tiles, 256, 0, stream>>>(x, ei, W1, b1, W2, b2, W3, b3, out);
  }
}

// Round 3
// 190.804 us; speedup vs baseline: 4.0400x; 1.6553x over previous
//
#include <hip/hip_runtime.h>
#include <hip/hip_bf16.h>

#define NNODES 50000
#define NFEAT  128
#define NEDGES 600000
#define HID    256
#define HID2   128
#define LEAKY  0.01f

typedef __attribute__((ext_vector_type(8))) short short8;
typedef __attribute__((ext_vector_type(4))) float floatx4;

// Truncation split: x ~= hi + lo (each bf16), residual ~2^-17 rel.
__device__ __forceinline__ void split_bf16(float x, unsigned short& hi, unsigned short& lo) {
  union { float f; unsigned u; } a; a.f = x;
  hi = (unsigned short)(a.u >> 16);
  union { float f; unsigned u; } h; h.u = (unsigned)hi << 16;
  union { float f; unsigned u; } r; r.f = x - h.f;
  lo = (unsigned short)(r.u >> 16);
}

// RNE fp32 -> bf16 (scalar)
__device__ __forceinline__ unsigned short bf16_rne(float x) {
  union { float f; unsigned u; } a; a.f = x;
  unsigned r = a.u + 0x7FFFu + ((a.u >> 16) & 1u);
  return (unsigned short)(r >> 16);
}

// RNE pack two fp32 -> u32 of 2 bf16 (a in low half) — compiler emits cvt_pk.
__device__ __forceinline__ unsigned pack2_rne(float a, float b) {
  __hip_bfloat162 h = __float22bfloat162_rn(make_float2(a, b));
  unsigned u; __builtin_memcpy(&u, &h, 4); return u;
}

__device__ __forceinline__ float ubits2f(unsigned u) {
  union { unsigned u; float f; } c; c.u = u; return c.f;
}

// ---------------------------------------------------------------------------
// pack_w2: W2 (256x128) -> MFMA B-frag order, bf16 hi/lo planes (32768 each).
// W2F[((ks*8+nf)*64 + l)*8 + i]: k = ks*32+(l>>4)*8+i, col = nf*16+(l&15).
// ---------------------------------------------------------------------------
__global__ __launch_bounds__(256) void pack_w2(const float* __restrict__ W2,
                                               unsigned short* __restrict__ W2F) {
  const int idx = blockIdx.x * 256 + threadIdx.x;
  if (idx >= 32768) return;
  const int i  = idx & 7;
  const int l  = (idx >> 3) & 63;
  const int nf = (idx >> 9) & 7;
  const int ks = idx >> 12;
  const int k   = ks * 32 + (l >> 4) * 8 + i;
  const int col = nf * 16 + (l & 15);
  unsigned short hi, lo;
  split_bf16(W2[k * HID2 + col], hi, lo);
  W2F[idx]         = hi;
  W2F[32768 + idx] = lo;
}

// ---------------------------------------------------------------------------
// pack_w1: W1' (128 x 512) -> B-frag order, bf16 hi/lo (65536 each).
// W1'[k][n] = n<256 ? W1[k][n] : W1[128+k][n-256].
// W1F[((ks*32+nf)*64 + l)*8 + i]: k = ks*32+(l>>4)*8+i, n = nf*16+(l&15).
// ---------------------------------------------------------------------------
__global__ __launch_bounds__(256) void pack_w1(const float* __restrict__ W1,
                                               unsigned short* __restrict__ W1F) {
  const int idx = blockIdx.x * 256 + threadIdx.x;
  if (idx >= 65536) return;
  const int i  = idx & 7;
  const int l  = (idx >> 3) & 63;
  const int nf = (idx >> 9) & 31;
  const int ks = idx >> 14;
  const int k = ks * 32 + (l >> 4) * 8 + i;
  const int n = nf * 16 + (l & 15);
  const float v = (n < 256) ? W1[k * HID + n] : W1[(128 + k) * HID + (n - 256)];
  unsigned short hi, lo;
  split_bf16(v, hi, lo);
  W1F[idx]         = hi;
  W1F[65536 + idx] = lo;
}

// ---------------------------------------------------------------------------
// pq_mfma: PQb[n][0:512] = bf16_rne( x[n] @ W1' )  via 3-term split MFMA.
// Block: 64 nodes x 256 cols (nhalf selects col half). 4 waves as 2x2:
// wave = rows rg*32..+32 (2 mf), cols cg*128..+128 (8 nf), K=128 (4 ks).
// ---------------------------------------------------------------------------
__global__ __launch_bounds__(256) void pq_mfma(
    const float* __restrict__ x, const unsigned short* __restrict__ W1F,
    unsigned short* __restrict__ PQb) {
  const int bid   = blockIdx.x;
  const int nhalf = bid & 1;
  const int n0    = (bid >> 1) * 64;
  const int t     = threadIdx.x;

  __shared__ __align__(16) unsigned short xhi[64 * 128];  // 16 KB swizzled
  __shared__ __align__(16) unsigned short xlo[64 * 128];  // 16 KB swizzled

  // stage x tile, split to bf16 hi/lo
#pragma unroll
  for (int rep = 0; rep < 8; ++rep) {
    const int flat = rep * 1024 + t * 4;
    const int row = flat >> 7, f0 = flat & 127;
    float4 v = make_float4(0.f, 0.f, 0.f, 0.f);
    if (n0 + row < NNODES)
      v = *reinterpret_cast<const float4*>(&x[(size_t)(n0 + row) * NFEAT + f0]);
    unsigned short h[4], l[4];
    split_bf16(v.x, h[0], l[0]); split_bf16(v.y, h[1], l[1]);
    split_bf16(v.z, h[2], l[2]); split_bf16(v.w, h[3], l[3]);
    const unsigned bt = (unsigned)(row * 256) +
                        (((unsigned)(2 * f0)) ^ (((unsigned)(row & 7)) << 4));
    *reinterpret_cast<uint2*>(reinterpret_cast<char*>(xhi) + bt) =
        make_uint2((unsigned)h[0] | ((unsigned)h[1] << 16),
                   (unsigned)h[2] | ((unsigned)h[3] << 16));
    *reinterpret_cast<uint2*>(reinterpret_cast<char*>(xlo) + bt) =
        make_uint2((unsigned)l[0] | ((unsigned)l[1] << 16),
                   (unsigned)l[2] | ((unsigned)l[3] << 16));
  }
  __syncthreads();

  const int wid = t >> 6, lane = t & 63;
  const int rg = wid >> 1, cg = wid & 1;
  const int lr = lane & 15, kc = lane >> 4;

  floatx4 acc[2][8];
#pragma unroll
  for (int mf = 0; mf < 2; ++mf)
#pragma unroll
    for (int nf = 0; nf < 8; ++nf) acc[mf][nf] = (floatx4)0.f;

#pragma unroll
  for (int ks = 0; ks < 4; ++ks) {
    short8 ah[2], al[2];
#pragma unroll
    for (int mf = 0; mf < 2; ++mf) {
      const int row = rg * 32 + mf * 16 + lr;
      const unsigned bt = (unsigned)(row * 256) +
                          (((unsigned)(ks * 64 + kc * 16)) ^ (((unsigned)(row & 7)) << 4));
      ah[mf] = *reinterpret_cast<const short8*>(reinterpret_cast<const char*>(xhi) + bt);
      al[mf] = *reinterpret_cast<const short8*>(reinterpret_cast<const char*>(xlo) + bt);
    }
#pragma unroll
    for (int nf = 0; nf < 8; ++nf) {
      const int nfg = nhalf * 16 + cg * 8 + nf;
      const size_t off = ((size_t)(ks * 32 + nfg) * 64 + lane) * 8;
      const short8 bh = *reinterpret_cast<const short8*>(W1F + off);
      const short8 bl = *reinterpret_cast<const short8*>(W1F + 65536 + off);
#pragma unroll
      for (int mf = 0; mf < 2; ++mf) {
        acc[mf][nf] = __builtin_amdgcn_mfma_f32_16x16x32_bf16(ah[mf], bh, acc[mf][nf], 0, 0, 0);
        acc[mf][nf] = __builtin_amdgcn_mfma_f32_16x16x32_bf16(ah[mf], bl, acc[mf][nf], 0, 0, 0);
        acc[mf][nf] = __builtin_amdgcn_mfma_f32_16x16x32_bf16(al[mf], bh, acc[mf][nf], 0, 0, 0);
      }
    }
  }

  // epilogue: RNE -> bf16, store. D: col=lane&15, row=(lane>>4)*4+r (+16*mf)
#pragma unroll
  for (int mf = 0; mf < 2; ++mf)
#pragma unroll
    for (int nf = 0; nf < 8; ++nf)
#pragma unroll
      for (int r = 0; r < 4; ++r) {
        const int node = n0 + rg * 32 + mf * 16 + kc * 4 + r;
        const int col  = nhalf * 256 + cg * 128 + nf * 16 + lr;
        if (node < NNODES) PQb[(size_t)node * 512 + col] = bf16_rne(acc[mf][nf][r]);
      }
}

// ---------------------------------------------------------------------------
// edge_mlp_mfma2: per 64-edge tile.
//   gather: h1[e][c] = rne_bf16(relu(P[r][c]+Q[c_][c]+b1[c])) into swizzled LDS
//   GEMM:   C(64x128) = h1 @ W2, 2-term (Ah*Bh + Ah*Bl)
//   epi:    out[e] = leakyrelu(C+b2) @ W3 + b3
// 4 waves; wave w: cols [32w,32w+32) (2 nf), all 64 rows (4 mf).
// ---------------------------------------------------------------------------
__global__ __launch_bounds__(256) void edge_mlp_mfma2(
    const int* __restrict__ ei, const float* __restrict__ b1,
    const unsigned short* __restrict__ W2F, const float* __restrict__ b2,
    const float* __restrict__ W3, const float* __restrict__ b3,
    const unsigned short* __restrict__ PQb, float* __restrict__ out) {
  const int t  = threadIdx.x;
  const int e0 = blockIdx.x * 64;

  __shared__ __align__(16) unsigned short h1s[64 * 256];  // 32 KB swizzled
  __shared__ int   eidx[2][64];
  __shared__ float outs[4][64];

  if (t < 64)       eidx[0][t]      = ei[e0 + t];
  else if (t < 128) eidx[1][t - 64] = ei[NEDGES + e0 + (t - 64)];
  __syncthreads();

  // ---- gather: thread owns cols [4c4, 4c4+4) for 16 edges ----
  {
    const int c4 = t & 63;
    const int eg = t >> 6;
    const float4 b1v = *reinterpret_cast<const float4*>(&b1[4 * c4]);
    const unsigned vo = (unsigned)(c4 * 8);
#pragma unroll 4
    for (int j = 0; j < 16; ++j) {
      const int e = eg * 16 + j;
      const int r  = __builtin_amdgcn_readfirstlane(eidx[0][e]);
      const int cc = __builtin_amdgcn_readfirstlane(eidx[1][e]);
      const uint2 pu = *reinterpret_cast<const uint2*>(
          reinterpret_cast<const char*>(PQb) + (size_t)r * 1024 + vo);
      const uint2 qu = *reinterpret_cast<const uint2*>(
          reinterpret_cast<const char*>(PQb) + (size_t)cc * 1024 + 512 + vo);
      const float v0 = fmaxf(ubits2f(pu.x << 16)          + ubits2f(qu.x << 16)          + b1v.x, 0.f);
      const float v1 = fmaxf(ubits2f(pu.x & 0xFFFF0000u)  + ubits2f(qu.x & 0xFFFF0000u)  + b1v.y, 0.f);
      const float v2 = fmaxf(ubits2f(pu.y << 16)          + ubits2f(qu.y << 16)          + b1v.z, 0.f);
      const float v3 = fmaxf(ubits2f(pu.y & 0xFFFF0000u)  + ubits2f(qu.y & 0xFFFF0000u)  + b1v.w, 0.f);
      const unsigned bt = (unsigned)(e * 512) + (vo ^ (((unsigned)(e & 7)) << 4));
      *reinterpret_cast<uint2*>(reinterpret_cast<char*>(h1s) + bt) =
          make_uint2(pack2_rne(v0, v1), pack2_rne(v2, v3));
    }
  }
  __syncthreads();

  // ---- MFMA ----
  const int wid = t >> 6, lane = t & 63;
  const int lr = lane & 15, kc = lane >> 4;

  floatx4 acc[4][2];
#pragma unroll
  for (int mf = 0; mf < 4; ++mf)
#pragma unroll
    for (int nf = 0; nf < 2; ++nf) acc[mf][nf] = (floatx4)0.f;

#pragma unroll
  for (int ks = 0; ks < 8; ++ks) {
    short8 ah[4];
#pragma unroll
    for (int mf = 0; mf < 4; ++mf) {
      const int row = mf * 16 + lr;
      const unsigned bt = (unsigned)(row * 512) +
                          (((unsigned)(ks * 64 + kc * 16)) ^ (((unsigned)(row & 7)) << 4));
      ah[mf] = *reinterpret_cast<const short8*>(reinterpret_cast<const char*>(h1s) + bt);
    }
    short8 bh[2], bl[2];
#pragma unroll
    for (int nf = 0; nf < 2; ++nf) {
      const int nfg = wid * 2 + nf;
      const size_t off = ((size_t)(ks * 8 + nfg) * 64 + lane) * 8;
      bh[nf] = *reinterpret_cast<const short8*>(W2F + off);
      bl[nf] = *reinterpret_cast<const short8*>(W2F + 32768 + off);
    }
#pragma unroll
    for (int mf = 0; mf < 4; ++mf)
#pragma unroll
      for (int nf = 0; nf < 2; ++nf) {
        acc[mf][nf] = __builtin_amdgcn_mfma_f32_16x16x32_bf16(ah[mf], bh[nf], acc[mf][nf], 0, 0, 0);
        acc[mf][nf] = __builtin_amdgcn_mfma_f32_16x16x32_bf16(ah[mf], bl[nf], acc[mf][nf], 0, 0, 0);
      }
  }

  // ---- epilogue ----
  float w3v[2], b2v[2];
#pragma unroll
  for (int nf = 0; nf < 2; ++nf) {
    const int col = wid * 32 + nf * 16 + lr;
    w3v[nf] = W3[col];
    b2v[nf] = b2[col];
  }

  float part[4][4];
#pragma unroll
  for (int mf = 0; mf < 4; ++mf)
#pragma unroll
    for (int r = 0; r < 4; ++r) {
      float s = 0.f;
#pragma unroll
      for (int nf = 0; nf < 2; ++nf) {
        float h = acc[mf][nf][r] + b2v[nf];
        h = (h > 0.f) ? h : LEAKY * h;
        s = fmaf(h, w3v[nf], s);
      }
      part[mf][r] = s;
    }

#pragma unroll
  for (int m = 1; m <= 8; m <<= 1)
#pragma unroll
    for (int mf = 0; mf < 4; ++mf)
#pragma unroll
      for (int r = 0; r < 4; ++r) part[mf][r] += __shfl_xor(part[mf][r], m, 64);

  if (lr == 0) {
#pragma unroll
    for (int mf = 0; mf < 4; ++mf)
#pragma unroll
      for (int r = 0; r < 4; ++r) outs[wid][mf * 16 + kc * 4 + r] = part[mf][r];
  }
  __syncthreads();

  if (t < 64) {
    out[e0 + t] = outs[0][t] + outs[1][t] + outs[2][t] + outs[3][t] + b3[0];
  }
}

// ---------------------------------------------------------------------------
// Fallback (ws too small): direct fp32 path, 32-edge tiles.
// ---------------------------------------------------------------------------
__global__ __launch_bounds__(256) void edge_mlp_direct(
    const float* __restrict__ x, const int* __restrict__ ei,
    const float* __restrict__ W1, const float* __restrict__ b1,
    const float* __restrict__ W2, const float* __restrict__ b2,
    const float* __restrict__ W3, const float* __restrict__ b3,
    float* __restrict__ out) {
  const int t  = threadIdx.x;
  const int e0 = blockIdx.x * 32;

  __shared__ __align__(16) float h1f[32 * HID];
  __shared__ int eidx[2][32];

  if (t < 32)      eidx[0][t]      = ei[e0 + t];
  else if (t < 64) eidx[1][t - 32] = ei[NEDGES + e0 + (t - 32)];
  __syncthreads();

  const float b1r = b1[t];
  __shared__ float xr[32][128];
  __shared__ float xc[32][128];
  for (int idx = t; idx < 32 * 128; idx += 256) {
    const int e = idx >> 7, f = idx & 127;
    xr[e][f] = x[(size_t)eidx[0][e] * NFEAT + f];
    xc[e][f] = x[(size_t)eidx[1][e] * NFEAT + f];
  }
  __syncthreads();
  float s[32];
#pragma unroll
  for (int e = 0; e < 32; ++e) s[e] = b1r;
  for (int f = 0; f < 128; ++f) {
    const float wr = W1[f * HID + t];
    const float wb = W1[(128 + f) * HID + t];
#pragma unroll
    for (int e = 0; e < 32; ++e)
      s[e] = fmaf(xr[e][f], wr, fmaf(xc[e][f], wb, s[e]));
  }
#pragma unroll
  for (int e = 0; e < 32; ++e) h1f[e * HID + t] = fmaxf(s[e], 0.f);
  __syncthreads();

  const int tr = t >> 5;
  const int tc = t & 31;
  float acc[4][4];
#pragma unroll
  for (int i = 0; i < 4; ++i)
#pragma unroll
    for (int j = 0; j < 4; ++j) acc[i][j] = 0.f;

  const float4* __restrict__ W2v = reinterpret_cast<const float4*>(W2);
  const float4* __restrict__ h1v = reinterpret_cast<const float4*>(h1f);
  for (int k = 0; k < HID; k += 4) {
    float4 a[4];
#pragma unroll
    for (int i = 0; i < 4; ++i) a[i] = h1v[((4 * tr + i) * HID + k) >> 2];
    float4 b[4];
#pragma unroll
    for (int kk = 0; kk < 4; ++kk) b[kk] = W2v[(k + kk) * 32 + tc];
#pragma unroll
    for (int i = 0; i < 4; ++i) {
      const float* av = reinterpret_cast<const float*>(&a[i]);
#pragma unroll
      for (int kk = 0; kk < 4; ++kk) {
        const float* bv = reinterpret_cast<const float*>(&b[kk]);
#pragma unroll
        for (int j = 0; j < 4; ++j) acc[i][j] = fmaf(av[kk], bv[j], acc[i][j]);
      }
    }
  }

  float w3r[4], b2r[4];
#pragma unroll
  for (int j = 0; j < 4; ++j) {
    w3r[j] = W3[4 * tc + j];
    b2r[j] = b2[4 * tc + j];
  }
  const float b3v = b3[0];
  float partial[4];
#pragma unroll
  for (int i = 0; i < 4; ++i) {
    float sp = 0.f;
#pragma unroll
    for (int j = 0; j < 4; ++j) {
      float h = acc[i][j] + b2r[j];
      h = (h > 0.f) ? h : LEAKY * h;
      sp = fmaf(h, w3r[j], sp);
    }
    partial[i] = sp;
  }
#pragma unroll
  for (int m = 16; m >= 1; m >>= 1)
#pragma unroll
    for (int i = 0; i < 4; ++i) partial[i] += __shfl_xor(partial[i], m, 32);
  if (tc == 0) {
#pragma unroll
    for (int i = 0; i < 4; ++i) out[e0 + 4 * tr + i] = partial[i] + b3v;
  }
}

extern "C" void kernel_launch(void* const* d_in, const int* in_sizes, int n_in,
                              void* d_out, int out_size, void* d_ws, size_t ws_size,
                              hipStream_t stream) {
  const float* x  = (const float*)d_in[0];
  const int*   ei = (const int*)d_in[1];
  const float* W1 = (const float*)d_in[2];
  const float* b1 = (const float*)d_in[3];
  const float* W2 = (const float*)d_in[4];
  const float* b2 = (const float*)d_in[5];
  const float* W3 = (const float*)d_in[6];
  const float* b3 = (const float*)d_in[7];
  float* out = (float*)d_out;

  const size_t pqb_bytes = (size_t)NNODES * 512 * 2;      // 51,200,000 (64-aligned)
  const size_t w2f_bytes = (size_t)2 * 32768 * 2;         // 131,072
  const size_t w1f_bytes = (size_t)2 * 65536 * 2;         // 262,144
  const size_t need = pqb_bytes + w2f_bytes + w1f_bytes;

  if (ws_size >= need) {
    unsigned short* PQb = (unsigned short*)d_ws;
    unsigned short* W2F = (unsigned short*)((char*)d_ws + pqb_bytes);
    unsigned short* W1F = (unsigned short*)((char*)d_ws + pqb_bytes + w2f_bytes);

    pack_w2<<<128, 256, 0, stream>>>(W2, W2F);
    pack_w1<<<256, 256, 0, stream>>>(W1, W1F);
    const int pq_blocks = ((NNODES + 63) / 64) * 2;       // 1564
    pq_mfma<<<pq_blocks, 256, 0, stream>>>(x, W1F, PQb);
    edge_mlp_mfma2<<<NEDGES / 64, 256, 0, stream>>>(ei, b1, W2F, b2, W3, b3, PQb, out);
  } else {
    edge_mlp_direct<<<NEDGES / 32, 256, 0, stream>>>(x, ei, W1, b1, W2, b2, W3, b3, out);
  }
}

// Round 4
// 175.273 us; speedup vs baseline: 4.3980x; 1.0886x over previous
//
#include <hip/hip_runtime.h>
#include <hip/hip_bf16.h>

#define NNODES 50000
#define NFEAT  128
#define NEDGES 600000
#define HID    256
#define HID2   128
#define LEAKY  0.01f

typedef __attribute__((ext_vector_type(8))) short short8;
typedef __attribute__((ext_vector_type(4))) float floatx4;

// Truncation split: x ~= hi + lo (each bf16), residual ~2^-17 rel.
__device__ __forceinline__ void split_bf16(float x, unsigned short& hi, unsigned short& lo) {
  union { float f; unsigned u; } a; a.f = x;
  hi = (unsigned short)(a.u >> 16);
  union { float f; unsigned u; } h; h.u = (unsigned)hi << 16;
  union { float f; unsigned u; } r; r.f = x - h.f;
  lo = (unsigned short)(r.u >> 16);
}

// RNE fp32 -> bf16 (scalar)
__device__ __forceinline__ unsigned short bf16_rne(float x) {
  union { float f; unsigned u; } a; a.f = x;
  unsigned r = a.u + 0x7FFFu + ((a.u >> 16) & 1u);
  return (unsigned short)(r >> 16);
}

// RNE pack two fp32 -> u32 of 2 bf16 (a in low half) — emits cvt_pk.
__device__ __forceinline__ unsigned pack2_rne(float a, float b) {
  __hip_bfloat162 h = __float22bfloat162_rn(make_float2(a, b));
  unsigned u; __builtin_memcpy(&u, &h, 4); return u;
}

__device__ __forceinline__ float ubits2f(unsigned u) {
  union { unsigned u; float f; } c; c.u = u; return c.f;
}

// ---------------------------------------------------------------------------
// pack_w: merged W2 + W1 packing into MFMA B-frag order, bf16 hi/lo planes.
// W2F[((ks*8+nf)*64+l)*8+i]:  k=ks*32+(l>>4)*8+i, col=nf*16+(l&15)   (32768/plane)
// W1F[((ks*32+nf)*64+l)*8+i]: k=ks*32+(l>>4)*8+i, n=nf*16+(l&15)     (65536/plane)
//   W1'[k][n] = n<256 ? W1[k][n] : W1[128+k][n-256]
// ---------------------------------------------------------------------------
__global__ __launch_bounds__(256) void pack_w(const float* __restrict__ W2,
                                              const float* __restrict__ W1,
                                              unsigned short* __restrict__ W2F,
                                              unsigned short* __restrict__ W1F) {
  const int gid = blockIdx.x * 256 + threadIdx.x;
  if (gid < 32768) {
    const int idx = gid;
    const int i  = idx & 7;
    const int l  = (idx >> 3) & 63;
    const int nf = (idx >> 9) & 7;
    const int ks = idx >> 12;
    const int k   = ks * 32 + (l >> 4) * 8 + i;
    const int col = nf * 16 + (l & 15);
    unsigned short hi, lo;
    split_bf16(W2[k * HID2 + col], hi, lo);
    W2F[idx]         = hi;
    W2F[32768 + idx] = lo;
  } else if (gid < 32768 + 65536) {
    const int idx = gid - 32768;
    const int i  = idx & 7;
    const int l  = (idx >> 3) & 63;
    const int nf = (idx >> 9) & 31;
    const int ks = idx >> 14;
    const int k = ks * 32 + (l >> 4) * 8 + i;
    const int n = nf * 16 + (l & 15);
    const float v = (n < 256) ? W1[k * HID + n] : W1[(128 + k) * HID + (n - 256)];
    unsigned short hi, lo;
    split_bf16(v, hi, lo);
    W1F[idx]         = hi;
    W1F[65536 + idx] = lo;
  }
}

// ---------------------------------------------------------------------------
// pq_mfma: PQb[n][0:512] = bf16_rne( x[n] @ W1' )  via 3-term split MFMA.
// Block: 64 nodes x 256 cols (nhalf). 4 waves as 2x2 (rows x col-groups).
// ---------------------------------------------------------------------------
__global__ __launch_bounds__(256) void pq_mfma(
    const float* __restrict__ x, const unsigned short* __restrict__ W1F,
    unsigned short* __restrict__ PQb) {
  const int bid   = blockIdx.x;
  const int nhalf = bid & 1;
  const int n0    = (bid >> 1) * 64;
  const int t     = threadIdx.x;

  __shared__ __align__(16) unsigned short xhi[64 * 128];  // 16 KB swizzled
  __shared__ __align__(16) unsigned short xlo[64 * 128];  // 16 KB swizzled

#pragma unroll
  for (int rep = 0; rep < 8; ++rep) {
    const int flat = rep * 1024 + t * 4;
    const int row = flat >> 7, f0 = flat & 127;
    float4 v = make_float4(0.f, 0.f, 0.f, 0.f);
    if (n0 + row < NNODES)
      v = *reinterpret_cast<const float4*>(&x[(size_t)(n0 + row) * NFEAT + f0]);
    unsigned short h[4], l[4];
    split_bf16(v.x, h[0], l[0]); split_bf16(v.y, h[1], l[1]);
    split_bf16(v.z, h[2], l[2]); split_bf16(v.w, h[3], l[3]);
    const unsigned bt = (unsigned)(row * 256) +
                        (((unsigned)(2 * f0)) ^ (((unsigned)(row & 7)) << 4));
    *reinterpret_cast<uint2*>(reinterpret_cast<char*>(xhi) + bt) =
        make_uint2((unsigned)h[0] | ((unsigned)h[1] << 16),
                   (unsigned)h[2] | ((unsigned)h[3] << 16));
    *reinterpret_cast<uint2*>(reinterpret_cast<char*>(xlo) + bt) =
        make_uint2((unsigned)l[0] | ((unsigned)l[1] << 16),
                   (unsigned)l[2] | ((unsigned)l[3] << 16));
  }
  __syncthreads();

  const int wid = t >> 6, lane = t & 63;
  const int rg = wid >> 1, cg = wid & 1;
  const int lr = lane & 15, kc = lane >> 4;

  floatx4 acc[2][8];
#pragma unroll
  for (int mf = 0; mf < 2; ++mf)
#pragma unroll
    for (int nf = 0; nf < 8; ++nf) acc[mf][nf] = (floatx4)0.f;

#pragma unroll
  for (int ks = 0; ks < 4; ++ks) {
    short8 ah[2], al[2];
#pragma unroll
    for (int mf = 0; mf < 2; ++mf) {
      const int row = rg * 32 + mf * 16 + lr;
      const unsigned bt = (unsigned)(row * 256) +
                          (((unsigned)(ks * 64 + kc * 16)) ^ (((unsigned)(row & 7)) << 4));
      ah[mf] = *reinterpret_cast<const short8*>(reinterpret_cast<const char*>(xhi) + bt);
      al[mf] = *reinterpret_cast<const short8*>(reinterpret_cast<const char*>(xlo) + bt);
    }
#pragma unroll
    for (int nf = 0; nf < 8; ++nf) {
      const int nfg = nhalf * 16 + cg * 8 + nf;
      const size_t off = ((size_t)(ks * 32 + nfg) * 64 + lane) * 8;
      const short8 bh = *reinterpret_cast<const short8*>(W1F + off);
      const short8 bl = *reinterpret_cast<const short8*>(W1F + 65536 + off);
#pragma unroll
      for (int mf = 0; mf < 2; ++mf) {
        acc[mf][nf] = __builtin_amdgcn_mfma_f32_16x16x32_bf16(ah[mf], bh, acc[mf][nf], 0, 0, 0);
        acc[mf][nf] = __builtin_amdgcn_mfma_f32_16x16x32_bf16(ah[mf], bl, acc[mf][nf], 0, 0, 0);
        acc[mf][nf] = __builtin_amdgcn_mfma_f32_16x16x32_bf16(al[mf], bh, acc[mf][nf], 0, 0, 0);
      }
    }
  }

#pragma unroll
  for (int mf = 0; mf < 2; ++mf)
#pragma unroll
    for (int nf = 0; nf < 8; ++nf)
#pragma unroll
      for (int r = 0; r < 4; ++r) {
        const int node = n0 + rg * 32 + mf * 16 + kc * 4 + r;
        const int col  = nhalf * 256 + cg * 128 + nf * 16 + lr;
        if (node < NNODES) PQb[(size_t)node * 512 + col] = bf16_rne(acc[mf][nf][r]);
      }
}

// ---------------------------------------------------------------------------
// edge_mlp_mfma3: per 64-edge tile.
//   gather: indices via v_readlane (SGPR base), 2-batch pipelined loads,
//           h1 = rne_bf16(relu(P+Q+b1)) into XOR-swizzled LDS
//   GEMM:   C(64x128) = h1 @ W2, 2-term (Ah*Bh + Ah*Bl)
//   epi:    out[e] = leakyrelu(C+b2) @ W3 + b3
// ---------------------------------------------------------------------------
__global__ __launch_bounds__(256) void edge_mlp_mfma3(
    const int* __restrict__ ei, const float* __restrict__ b1,
    const unsigned short* __restrict__ W2F, const float* __restrict__ b2,
    const float* __restrict__ W3, const float* __restrict__ b3,
    const unsigned short* __restrict__ PQb, float* __restrict__ out) {
  const int t  = threadIdx.x;
  const int e0 = blockIdx.x * 64;
  const int wid = t >> 6, lane = t & 63;

  __shared__ __align__(16) unsigned short h1s[64 * 256];  // 32 KB swizzled
  __shared__ float outs[4][64];

  // ---- gather: wave `wid` owns edges [16*wid, 16*wid+16), cols via lane ----
  {
    const unsigned vo = (unsigned)(lane * 8);   // byte offset: cols [4*lane,4*lane+4)
    const float4 b1v = *reinterpret_cast<const float4*>(&b1[4 * lane]);
    // wave-local index vector: lanes 0-15 hold this wave's 16 edges
    const int rv = ei[e0 + wid * 16 + (lane & 15)];
    const int cv = ei[NEDGES + e0 + wid * 16 + (lane & 15)];
    const char* PQc = reinterpret_cast<const char*>(PQb);

    uint2 P0[8], Q0[8], P1[8], Q1[8];
#pragma unroll
    for (int j = 0; j < 8; ++j) {
      const int r = __builtin_amdgcn_readlane(rv, j);
      const int c = __builtin_amdgcn_readlane(cv, j);
      P0[j] = *reinterpret_cast<const uint2*>(PQc + (size_t)r * 1024 + vo);
      Q0[j] = *reinterpret_cast<const uint2*>(PQc + (size_t)c * 1024 + 512 + vo);
    }
#pragma unroll
    for (int j = 0; j < 8; ++j) {
      const int r = __builtin_amdgcn_readlane(rv, 8 + j);
      const int c = __builtin_amdgcn_readlane(cv, 8 + j);
      P1[j] = *reinterpret_cast<const uint2*>(PQc + (size_t)r * 1024 + vo);
      Q1[j] = *reinterpret_cast<const uint2*>(PQc + (size_t)c * 1024 + 512 + vo);
    }

#pragma unroll
    for (int j = 0; j < 8; ++j) {
      const uint2 pu = P0[j], qu = Q0[j];
      const float v0 = fmaxf(ubits2f(pu.x << 16)         + ubits2f(qu.x << 16)         + b1v.x, 0.f);
      const float v1 = fmaxf(ubits2f(pu.x & 0xFFFF0000u) + ubits2f(qu.x & 0xFFFF0000u) + b1v.y, 0.f);
      const float v2 = fmaxf(ubits2f(pu.y << 16)         + ubits2f(qu.y << 16)         + b1v.z, 0.f);
      const float v3 = fmaxf(ubits2f(pu.y & 0xFFFF0000u) + ubits2f(qu.y & 0xFFFF0000u) + b1v.w, 0.f);
      const int e = wid * 16 + j;
      const unsigned bt = (unsigned)(e * 512) + (vo ^ (((unsigned)(e & 7)) << 4));
      *reinterpret_cast<uint2*>(reinterpret_cast<char*>(h1s) + bt) =
          make_uint2(pack2_rne(v0, v1), pack2_rne(v2, v3));
    }
#pragma unroll
    for (int j = 0; j < 8; ++j) {
      const uint2 pu = P1[j], qu = Q1[j];
      const float v0 = fmaxf(ubits2f(pu.x << 16)         + ubits2f(qu.x << 16)         + b1v.x, 0.f);
      const float v1 = fmaxf(ubits2f(pu.x & 0xFFFF0000u) + ubits2f(qu.x & 0xFFFF0000u) + b1v.y, 0.f);
      const float v2 = fmaxf(ubits2f(pu.y << 16)         + ubits2f(qu.y << 16)         + b1v.z, 0.f);
      const float v3 = fmaxf(ubits2f(pu.y & 0xFFFF0000u) + ubits2f(qu.y & 0xFFFF0000u) + b1v.w, 0.f);
      const int e = wid * 16 + 8 + j;
      const unsigned bt = (unsigned)(e * 512) + (vo ^ (((unsigned)(e & 7)) << 4));
      *reinterpret_cast<uint2*>(reinterpret_cast<char*>(h1s) + bt) =
          make_uint2(pack2_rne(v0, v1), pack2_rne(v2, v3));
    }
  }
  __syncthreads();

  // ---- MFMA: wave w -> cols [32w,32w+32) (2 nf), all 64 rows (4 mf) ----
  const int lr = lane & 15, kc = lane >> 4;

  floatx4 acc[4][2];
#pragma unroll
  for (int mf = 0; mf < 4; ++mf)
#pragma unroll
    for (int nf = 0; nf < 2; ++nf) acc[mf][nf] = (floatx4)0.f;

#pragma unroll
  for (int ks = 0; ks < 8; ++ks) {
    short8 ah[4];
#pragma unroll
    for (int mf = 0; mf < 4; ++mf) {
      const int row = mf * 16 + lr;
      const unsigned bt = (unsigned)(row * 512) +
                          (((unsigned)(ks * 64 + kc * 16)) ^ (((unsigned)(row & 7)) << 4));
      ah[mf] = *reinterpret_cast<const short8*>(reinterpret_cast<const char*>(h1s) + bt);
    }
    short8 bh[2], bl[2];
#pragma unroll
    for (int nf = 0; nf < 2; ++nf) {
      const int nfg = wid * 2 + nf;
      const size_t off = ((size_t)(ks * 8 + nfg) * 64 + lane) * 8;
      bh[nf] = *reinterpret_cast<const short8*>(W2F + off);
      bl[nf] = *reinterpret_cast<const short8*>(W2F + 32768 + off);
    }
#pragma unroll
    for (int mf = 0; mf < 4; ++mf)
#pragma unroll
      for (int nf = 0; nf < 2; ++nf) {
        acc[mf][nf] = __builtin_amdgcn_mfma_f32_16x16x32_bf16(ah[mf], bh[nf], acc[mf][nf], 0, 0, 0);
        acc[mf][nf] = __builtin_amdgcn_mfma_f32_16x16x32_bf16(ah[mf], bl[nf], acc[mf][nf], 0, 0, 0);
      }
  }

  // ---- epilogue ----
  float w3v[2], b2v[2];
#pragma unroll
  for (int nf = 0; nf < 2; ++nf) {
    const int col = wid * 32 + nf * 16 + lr;
    w3v[nf] = W3[col];
    b2v[nf] = b2[col];
  }

  float part[4][4];
#pragma unroll
  for (int mf = 0; mf < 4; ++mf)
#pragma unroll
    for (int r = 0; r < 4; ++r) {
      float s = 0.f;
#pragma unroll
      for (int nf = 0; nf < 2; ++nf) {
        float h = acc[mf][nf][r] + b2v[nf];
        h = (h > 0.f) ? h : LEAKY * h;
        s = fmaf(h, w3v[nf], s);
      }
      part[mf][r] = s;
    }

#pragma unroll
  for (int m = 1; m <= 8; m <<= 1)
#pragma unroll
    for (int mf = 0; mf < 4; ++mf)
#pragma unroll
      for (int r = 0; r < 4; ++r) part[mf][r] += __shfl_xor(part[mf][r], m, 64);

  if (lr == 0) {
#pragma unroll
    for (int mf = 0; mf < 4; ++mf)
#pragma unroll
      for (int r = 0; r < 4; ++r) outs[wid][mf * 16 + kc * 4 + r] = part[mf][r];
  }
  __syncthreads();

  if (t < 64) {
    out[e0 + t] = outs[0][t] + outs[1][t] + outs[2][t] + outs[3][t] + b3[0];
  }
}

// ---------------------------------------------------------------------------
// Fallback (ws too small): direct fp32 path, 32-edge tiles.
// ---------------------------------------------------------------------------
__global__ __launch_bounds__(256) void edge_mlp_direct(
    const float* __restrict__ x, const int* __restrict__ ei,
    const float* __restrict__ W1, const float* __restrict__ b1,
    const float* __restrict__ W2, const float* __restrict__ b2,
    const float* __restrict__ W3, const float* __restrict__ b3,
    float* __restrict__ out) {
  const int t  = threadIdx.x;
  const int e0 = blockIdx.x * 32;

  __shared__ __align__(16) float h1f[32 * HID];
  __shared__ int eidx[2][32];

  if (t < 32)      eidx[0][t]      = ei[e0 + t];
  else if (t < 64) eidx[1][t - 32] = ei[NEDGES + e0 + (t - 32)];
  __syncthreads();

  const float b1r = b1[t];
  __shared__ float xr[32][128];
  __shared__ float xc[32][128];
  for (int idx = t; idx < 32 * 128; idx += 256) {
    const int e = idx >> 7, f = idx & 127;
    xr[e][f] = x[(size_t)eidx[0][e] * NFEAT + f];
    xc[e][f] = x[(size_t)eidx[1][e] * NFEAT + f];
  }
  __syncthreads();
  float s[32];
#pragma unroll
  for (int e = 0; e < 32; ++e) s[e] = b1r;
  for (int f = 0; f < 128; ++f) {
    const float wr = W1[f * HID + t];
    const float wb = W1[(128 + f) * HID + t];
#pragma unroll
    for (int e = 0; e < 32; ++e)
      s[e] = fmaf(xr[e][f], wr, fmaf(xc[e][f], wb, s[e]));
  }
#pragma unroll
  for (int e = 0; e < 32; ++e) h1f[e * HID + t] = fmaxf(s[e], 0.f);
  __syncthreads();

  const int tr = t >> 5;
  const int tc = t & 31;
  float acc[4][4];
#pragma unroll
  for (int i = 0; i < 4; ++i)
#pragma unroll
    for (int j = 0; j < 4; ++j) acc[i][j] = 0.f;

  const float4* __restrict__ W2v = reinterpret_cast<const float4*>(W2);
  const float4* __restrict__ h1v = reinterpret_cast<const float4*>(h1f);
  for (int k = 0; k < HID; k += 4) {
    float4 a[4];
#pragma unroll
    for (int i = 0; i < 4; ++i) a[i] = h1v[((4 * tr + i) * HID + k) >> 2];
    float4 b[4];
#pragma unroll
    for (int kk = 0; kk < 4; ++kk) b[kk] = W2v[(k + kk) * 32 + tc];
#pragma unroll
    for (int i = 0; i < 4; ++i) {
      const float* av = reinterpret_cast<const float*>(&a[i]);
#pragma unroll
      for (int kk = 0; kk < 4; ++kk) {
        const float* bv = reinterpret_cast<const float*>(&b[kk]);
#pragma unroll
        for (int j = 0; j < 4; ++j) acc[i][j] = fmaf(av[kk], bv[j], acc[i][j]);
      }
    }
  }

  float w3r[4], b2r[4];
#pragma unroll
  for (int j = 0; j < 4; ++j) {
    w3r[j] = W3[4 * tc + j];
    b2r[j] = b2[4 * tc + j];
  }
  const float b3v = b3[0];
  float partial[4];
#pragma unroll
  for (int i = 0; i < 4; ++i) {
    float sp = 0.f;
#pragma unroll
    for (int j = 0; j < 4; ++j) {
      float h = acc[i][j] + b2r[j];
      h = (h > 0.f) ? h : LEAKY * h;
      sp = fmaf(h, w3r[j], sp);
    }
    partial[i] = sp;
  }
#pragma unroll
  for (int m = 16; m >= 1; m >>= 1)
#pragma unroll
    for (int i = 0; i < 4; ++i) partial[i] += __shfl_xor(partial[i], m, 32);
  if (tc == 0) {
#pragma unroll
    for (int i = 0; i < 4; ++i) out[e0 + 4 * tr + i] = partial[i] + b3v;
  }
}

extern "C" void kernel_launch(void* const* d_in, const int* in_sizes, int n_in,
                              void* d_out, int out_size, void* d_ws, size_t ws_size,
                              hipStream_t stream) {
  const float* x  = (const float*)d_in[0];
  const int*   ei = (const int*)d_in[1];
  const float* W1 = (const float*)d_in[2];
  const float* b1 = (const float*)d_in[3];
  const float* W2 = (const float*)d_in[4];
  const float* b2 = (const float*)d_in[5];
  const float* W3 = (const float*)d_in[6];
  const float* b3 = (const float*)d_in[7];
  float* out = (float*)d_out;

  const size_t pqb_bytes = (size_t)NNODES * 512 * 2;      // 51,200,000
  const size_t w2f_bytes = (size_t)2 * 32768 * 2;         // 131,072
  const size_t w1f_bytes = (size_t)2 * 65536 * 2;         // 262,144
  const size_t need = pqb_bytes + w2f_bytes + w1f_bytes;

  if (ws_size >= need) {
    unsigned short* PQb = (unsigned short*)d_ws;
    unsigned short* W2F = (unsigned short*)((char*)d_ws + pqb_bytes);
    unsigned short* W1F = (unsigned short*)((char*)d_ws + pqb_bytes + w2f_bytes);

    pack_w<<<(32768 + 65536 + 255) / 256, 256, 0, stream>>>(W2, W1, W2F, W1F);
    const int pq_blocks = ((NNODES + 63) / 64) * 2;       // 1564
    pq_mfma<<<pq_blocks, 256, 0, stream>>>(x, W1F, PQb);
    edge_mlp_mfma3<<<NEDGES / 64, 256, 0, stream>>>(ei, b1, W2F, b2, W3, b3, PQb, out);
  } else {
    edge_mlp_direct<<<NEDGES / 32, 256, 0, stream>>>(x, ei, W1, b1, W2, b2, W3, b3, out);
  }
}